// Round 1
// baseline (2549.596 us; speedup 1.0000x reference)
//
#include <hip/hip_runtime.h>
#include <math.h>

#define NSWEEPS 8

__device__ __forceinline__ float fshfl_xor(float v, int m) {
  return __shfl_xor(v, m, 64);
}

// One parallel-Jacobi round: pairs (lane, lane^R) within each 16-lane group.
// a[16] = this lane's column of the 16x16 matrix; nn = maintained ||col||^2.
template<int R>
__device__ __forceinline__ void jround(float (&a)[16], float &nn, const int lane) {
  const float on = fshfl_xor(nn, R);
  float oth[16];
#pragma unroll
  for (int i = 0; i < 16; ++i) oth[i] = fshfl_xor(a[i], R);
  float apq = 0.0f;
#pragma unroll
  for (int i = 0; i < 16; ++i) apq = fmaf(a[i], oth[i], apq);
  const bool lo = lane < (lane ^ R);          // consistent p/q role in the pair
  const float app = lo ? nn : on;
  const float aqq = lo ? on : nn;
  // Jacobi rotation zeroing apq (Golub & Van Loan):
  float tau = (aqq - app) * __builtin_amdgcn_rcpf(2.0f * apq);
  float t = copysignf(
      __builtin_amdgcn_rcpf(fabsf(tau) + __builtin_amdgcn_sqrtf(fmaf(tau, tau, 1.0f))), tau);
  t = (apq == 0.0f) ? 0.0f : t;               // also guards the NaN path
  const float c  = __builtin_amdgcn_rsqf(fmaf(t, t, 1.0f));
  const float s  = t * c;
  const float se = lo ? -s : s;
  const float ts = lo ? -t : t;
#pragma unroll
  for (int i = 0; i < 16; ++i) a[i] = fmaf(c, a[i], se * oth[i]);
  nn = fmaf(ts, apq, nn);                     // app' = app - t*apq ; aqq' = aqq + t*apq
}

__device__ __forceinline__ void jsweep(float (&a)[16], float &nn, const int lane) {
  jround<1>(a, nn, lane);  jround<2>(a, nn, lane);  jround<3>(a, nn, lane);
  jround<4>(a, nn, lane);  jround<5>(a, nn, lane);  jround<6>(a, nn, lane);
  jround<7>(a, nn, lane);  jround<8>(a, nn, lane);  jround<9>(a, nn, lane);
  jround<10>(a, nn, lane); jround<11>(a, nn, lane); jround<12>(a, nn, lane);
  jround<13>(a, nn, lane); jround<14>(a, nn, lane); jround<15>(a, nn, lane);
}

// Load one 16x16 patch matrix (lane = column index; each lane's column is a
// contiguous 64B row of the feature map), run one-sided Jacobi, sort columns
// by descending sigma^2 across the group. Returns this lane's sigma^2; a[]
// holds the (unnormalized) column sigma_j * u_j at sorted position = lane.
__device__ __forceinline__ float svd16(const float* __restrict__ src, float (&a)[16],
                                       const int lane, const int wl) {
  const float4* p = (const float4*)src;
  float4 v0 = p[0], v1 = p[1], v2 = p[2], v3 = p[3];
  a[0] = v0.x; a[1] = v0.y; a[2]  = v0.z; a[3]  = v0.w;
  a[4] = v1.x; a[5] = v1.y; a[6]  = v1.z; a[7]  = v1.w;
  a[8] = v2.x; a[9] = v2.y; a[10] = v2.z; a[11] = v2.w;
  a[12] = v3.x; a[13] = v3.y; a[14] = v3.z; a[15] = v3.w;

  float nn = 0.0f;
#pragma unroll
  for (int i = 0; i < 16; ++i) nn = fmaf(a[i], a[i], nn);
  for (int sw = 0; sw < NSWEEPS; ++sw) jsweep(a, nn, lane);

  float s2 = 0.0f;                            // exact sigma^2 (recomputed)
#pragma unroll
  for (int i = 0; i < 16; ++i) s2 = fmaf(a[i], a[i], s2);

  int rank = 0;                               // descending, stable tie-break
#pragma unroll
  for (int k = 0; k < 16; ++k) {
    const float vk = __shfl(s2, k, 16);
    rank += (vk > s2 || (vk == s2 && k < lane)) ? 1 : 0;
  }
  const int dst = (((wl & 48) | rank) << 2);  // wave-lane byte address for ds_permute (push)
#pragma unroll
  for (int i = 0; i < 16; ++i)
    a[i] = __int_as_float(__builtin_amdgcn_ds_permute(dst, __float_as_int(a[i])));
  s2 = __int_as_float(__builtin_amdgcn_ds_permute(dst, __float_as_int(s2)));
  return s2;
}

template<int CH, int H, int W, int NH, int NW>
__global__ __launch_bounds__(256)
void svd_layer_kernel(const float* __restrict__ ref, const float* __restrict__ dist,
                      float* __restrict__ dsSum) {
  constexpr int P = NH * NW;
  const int tid  = threadIdx.x;
  const int lane = tid & 15;
  const int wl   = tid & 63;
  const int pid  = blockIdx.x * 16 + (tid >> 4);
  const int ai   = pid / (CH * P);
  const int rem  = pid - ai * (CH * P);
  const int ch   = rem / P;
  const int pp   = rem - ch * P;
  const int ih   = pp / NW;
  const int iw   = pp - ih * NW;
  // patch matrix M[t][s] = x[ih*4+s, iw*4+t]; lane = column s -> row (ih*4+lane) of x
  const size_t off = (size_t)(ai * CH + ch) * (H * W) + (size_t)(ih * 4 + lane) * W + iw * 4;

  float ar[16];
  const float s2r = svd16(ref + off, ar, lane, wl);
  float ad[16];
  const float s2d = svd16(dist + off, ad, lane, wl);

  // sum_j (sigma_r - sigma_d)^2 over sorted singular values
  const float sigr = __builtin_amdgcn_sqrtf(s2r);
  const float sigd = __builtin_amdgcn_sqrtf(s2d);
  const float dd = sigr - sigd;
  float diffs = dd * dd;
#pragma unroll
  for (int st = 1; st < 16; st <<= 1) diffs += fshfl_xor(diffs, st);

  // u_rd_i = sum_j |u_r[i,j] * u_d[i,j]|  (normalize via 1/(sigr_j*sigd_j))
  const float inv = __builtin_amdgcn_rsqf(s2r * s2d);
  float prd[16];
#pragma unroll
  for (int i = 0; i < 16; ++i) prd[i] = fabsf(ar[i] * ad[i]) * inv;
#pragma unroll
  for (int st = 1; st < 16; st <<= 1) {
#pragma unroll
    for (int i = 0; i < 16; ++i) prd[i] += fshfl_xor(prd[i], st);
  }
  float sum = 0.0f, sumsq = 0.0f;
#pragma unroll
  for (int i = 0; i < 16; ++i) { sum += prd[i]; sumsq = fmaf(prd[i], prd[i], sumsq); }
  const float mean = sum * 0.0625f;
  float var = (sumsq - 16.0f * mean * mean) * (1.0f / 15.0f);  // ddof=1
  var = fmaxf(var, 0.0f);
  const float wt  = __builtin_amdgcn_sqrtf(var) * __builtin_amdgcn_rcpf(mean + 1e-9f);
  const float val = diffs * wt;

  __shared__ float blk;
  if (tid == 0) blk = 0.0f;
  __syncthreads();
  if (lane == 0) atomicAdd(&blk, val);
  __syncthreads();
  if (tid == 0) atomicAdd(&dsSum[ai], blk);   // all groups in a block share 'ai'
}

template<int CH, int HW>
__global__ __launch_bounds__(256)
void glb_kernel(const float* __restrict__ ref, const float* __restrict__ dist,
                float* __restrict__ s1Sum) {
  const int bid = blockIdx.x;                 // a*CH + ch
  const int ai  = bid / CH;
  const float4* pr = (const float4*)(ref + (size_t)bid * HW);
  const float4* pd = (const float4*)(dist + (size_t)bid * HW);
  float sr = 0.0f, sd = 0.0f;
  for (int i = threadIdx.x; i < HW / 4; i += 256) {
    const float4 r = pr[i], d = pd[i];
    sr += (r.x + r.y) + (r.z + r.w);
    sd += (d.x + d.y) + (d.z + d.w);
  }
#pragma unroll
  for (int st = 32; st >= 1; st >>= 1) { sr += __shfl_xor(sr, st, 64); sd += __shfl_xor(sd, st, 64); }
  __shared__ float bufR[4], bufD[4];
  const int w = threadIdx.x >> 6;
  if ((threadIdx.x & 63) == 0) { bufR[w] = sr; bufD[w] = sd; }
  __syncthreads();
  if (threadIdx.x == 0) {
    const float ym = (bufR[0] + bufR[1] + bufR[2] + bufR[3]) * (1.0f / HW);  // ref mean
    const float xm = (bufD[0] + bufD[1] + bufD[2] + bufD[3]) * (1.0f / HW);  // dist mean
    const float s1 = (2.0f * xm * ym + 1e-6f) / (xm * xm + ym * ym + 1e-6f);
    atomicAdd(&s1Sum[ai], s1);
  }
}

__global__ void final_kernel(const float* __restrict__ ws, float* __restrict__ out) {
  const int ai = threadIdx.x;
  if (ai < 4) {
    const float ds3 = ws[ai]      * (1.0f / (256.0f * 169.0f));
    const float ds4 = ws[4 + ai]  * (1.0f / (512.0f * 25.0f));
    const float g3  = expf(-2.0f * ws[8 + ai]  * (1.0f / 256.0f));
    const float g4  = expf(-2.0f * ws[12 + ai] * (1.0f / 512.0f));
    out[ai] = ds3 * g3 + ds4 * g4;
  }
}

extern "C" void kernel_launch(void* const* d_in, const int* in_sizes, int n_in,
                              void* d_out, int out_size, void* d_ws, size_t ws_size,
                              hipStream_t stream) {
  const float* ref3  = (const float*)d_in[0];
  const float* dist3 = (const float*)d_in[1];
  const float* ref4  = (const float*)d_in[2];
  const float* dist4 = (const float*)d_in[3];
  float* ws  = (float*)d_ws;   // [0:4) dsSum3, [4:8) dsSum4, [8:12) s1Sum3, [12:16) s1Sum4
  float* out = (float*)d_out;

  hipMemsetAsync(ws, 0, 16 * sizeof(float), stream);

  // feat3: 4*256*169 = 173056 patch pairs, 16 per block
  svd_layer_kernel<256, 64, 64, 13, 13><<<173056 / 16, 256, 0, stream>>>(ref3, dist3, ws + 0);
  // feat4: 4*512*25 = 51200 patch pairs
  svd_layer_kernel<512, 32, 32, 5, 5><<<51200 / 16, 256, 0, stream>>>(ref4, dist4, ws + 4);

  glb_kernel<256, 4096><<<4 * 256, 256, 0, stream>>>(ref3, dist3, ws + 8);
  glb_kernel<512, 1024><<<4 * 512, 256, 0, stream>>>(ref4, dist4, ws + 12);

  final_kernel<<<1, 64, 0, stream>>>(ws, out);
}

// Round 2
// 2002.729 us; speedup vs baseline: 1.2731x; 1.2731x over previous
//
#include <hip/hip_runtime.h>
#include <math.h>

#define NSWEEPS 6

__device__ __forceinline__ float fshfl_xor(float v, int m) {
  return __shfl_xor(v, m, 64);
}

// Jacobi rotation parameters zeroing apq (Golub & Van Loan).
__device__ __forceinline__ void jrot(float apq, float app, float aqq, bool lo,
                                     float &c, float &se, float &ts) {
  float tau = (aqq - app) * __builtin_amdgcn_rcpf(2.0f * apq);
  float t = copysignf(
      __builtin_amdgcn_rcpf(fabsf(tau) + __builtin_amdgcn_sqrtf(fmaf(tau, tau, 1.0f))), tau);
  t = (apq == 0.0f) ? 0.0f : t;               // also guards the NaN path
  c = __builtin_amdgcn_rsqf(fmaf(t, t, 1.0f));
  const float s = t * c;
  se = lo ? -s : s;
  ts = lo ? -t : t;
}

// One parallel-Jacobi round over TWO independent matrices (ref & dist),
// interleaved for ILP. Pairs (lane, lane^R) within each 16-lane group.
template<int R>
__device__ __forceinline__ void jround2(float (&a)[16], float &nna,
                                        float (&b)[16], float &nnb, const int lane) {
  const float ona = fshfl_xor(nna, R);
  const float onb = fshfl_xor(nnb, R);
  float otha[16], othb[16];
#pragma unroll
  for (int i = 0; i < 16; ++i) otha[i] = fshfl_xor(a[i], R);
#pragma unroll
  for (int i = 0; i < 16; ++i) othb[i] = fshfl_xor(b[i], R);

  // Dot products with 4-way split accumulators (short dependency chains).
  float pa0 = 0.f, pa1 = 0.f, pa2 = 0.f, pa3 = 0.f;
  float pb0 = 0.f, pb1 = 0.f, pb2 = 0.f, pb3 = 0.f;
#pragma unroll
  for (int i = 0; i < 16; i += 4) {
    pa0 = fmaf(a[i + 0], otha[i + 0], pa0);
    pa1 = fmaf(a[i + 1], otha[i + 1], pa1);
    pa2 = fmaf(a[i + 2], otha[i + 2], pa2);
    pa3 = fmaf(a[i + 3], otha[i + 3], pa3);
    pb0 = fmaf(b[i + 0], othb[i + 0], pb0);
    pb1 = fmaf(b[i + 1], othb[i + 1], pb1);
    pb2 = fmaf(b[i + 2], othb[i + 2], pb2);
    pb3 = fmaf(b[i + 3], othb[i + 3], pb3);
  }
  const float apqa = (pa0 + pa1) + (pa2 + pa3);
  const float apqb = (pb0 + pb1) + (pb2 + pb3);

  const bool lo = lane < (lane ^ R);          // consistent p/q role in the pair
  float ca, sea, tsa, cb, seb, tsb;
  jrot(apqa, lo ? nna : ona, lo ? ona : nna, lo, ca, sea, tsa);
  jrot(apqb, lo ? nnb : onb, lo ? onb : nnb, lo, cb, seb, tsb);

#pragma unroll
  for (int i = 0; i < 16; ++i) a[i] = fmaf(ca, a[i], sea * otha[i]);
#pragma unroll
  for (int i = 0; i < 16; ++i) b[i] = fmaf(cb, b[i], seb * othb[i]);
  nna = fmaf(tsa, apqa, nna);                 // app' = app - t*apq ; aqq' = aqq + t*apq
  nnb = fmaf(tsb, apqb, nnb);
}

__device__ __forceinline__ void jsweep2(float (&a)[16], float &nna,
                                        float (&b)[16], float &nnb, const int lane) {
  jround2<1>(a, nna, b, nnb, lane);  jround2<2>(a, nna, b, nnb, lane);
  jround2<3>(a, nna, b, nnb, lane);  jround2<4>(a, nna, b, nnb, lane);
  jround2<5>(a, nna, b, nnb, lane);  jround2<6>(a, nna, b, nnb, lane);
  jround2<7>(a, nna, b, nnb, lane);  jround2<8>(a, nna, b, nnb, lane);
  jround2<9>(a, nna, b, nnb, lane);  jround2<10>(a, nna, b, nnb, lane);
  jround2<11>(a, nna, b, nnb, lane); jround2<12>(a, nna, b, nnb, lane);
  jround2<13>(a, nna, b, nnb, lane); jround2<14>(a, nna, b, nnb, lane);
  jround2<15>(a, nna, b, nnb, lane);
}

__device__ __forceinline__ void load16(const float* __restrict__ src, float (&a)[16]) {
  const float4* p = (const float4*)src;
  float4 v0 = p[0], v1 = p[1], v2 = p[2], v3 = p[3];
  a[0] = v0.x; a[1] = v0.y; a[2]  = v0.z; a[3]  = v0.w;
  a[4] = v1.x; a[5] = v1.y; a[6]  = v1.z; a[7]  = v1.w;
  a[8] = v2.x; a[9] = v2.y; a[10] = v2.z; a[11] = v2.w;
  a[12] = v3.x; a[13] = v3.y; a[14] = v3.z; a[15] = v3.w;
}

// Post-convergence: exact sigma^2 + descending sort of columns across the
// 16-lane group via ds_permute push. a[] ends at sorted position = lane.
__device__ __forceinline__ float sort16(float (&a)[16], const int lane, const int wl) {
  float s0 = 0.f, s1 = 0.f, s2v = 0.f, s3 = 0.f;
#pragma unroll
  for (int i = 0; i < 16; i += 4) {
    s0 = fmaf(a[i + 0], a[i + 0], s0);
    s1 = fmaf(a[i + 1], a[i + 1], s1);
    s2v = fmaf(a[i + 2], a[i + 2], s2v);
    s3 = fmaf(a[i + 3], a[i + 3], s3);
  }
  float s2 = (s0 + s1) + (s2v + s3);

  int rank = 0;                               // descending, stable tie-break
#pragma unroll
  for (int k = 0; k < 16; ++k) {
    const float vk = __shfl(s2, k, 16);
    rank += (vk > s2 || (vk == s2 && k < lane)) ? 1 : 0;
  }
  const int dst = (((wl & 48) | rank) << 2);  // wave-lane byte address for ds_permute (push)
#pragma unroll
  for (int i = 0; i < 16; ++i)
    a[i] = __int_as_float(__builtin_amdgcn_ds_permute(dst, __float_as_int(a[i])));
  s2 = __int_as_float(__builtin_amdgcn_ds_permute(dst, __float_as_int(s2)));
  return s2;
}

template<int CH, int H, int W, int NH, int NW>
__global__ __launch_bounds__(256)
void svd_layer_kernel(const float* __restrict__ ref, const float* __restrict__ dist,
                      float* __restrict__ dsSum) {
  constexpr int P = NH * NW;
  const int tid  = threadIdx.x;
  const int lane = tid & 15;
  const int wl   = tid & 63;
  const int pid  = blockIdx.x * 16 + (tid >> 4);
  const int ai   = pid / (CH * P);
  const int rem  = pid - ai * (CH * P);
  const int ch   = rem / P;
  const int pp   = rem - ch * P;
  const int ih   = pp / NW;
  const int iw   = pp - ih * NW;
  // patch matrix M[t][s] = x[ih*4+s, iw*4+t]; lane = column s -> row (ih*4+lane) of x
  const size_t off = (size_t)(ai * CH + ch) * (H * W) + (size_t)(ih * 4 + lane) * W + iw * 4;

  float ar[16], ad[16];
  load16(ref + off, ar);
  load16(dist + off, ad);

  float nnr = 0.f, nnd = 0.f;
#pragma unroll
  for (int i = 0; i < 16; ++i) { nnr = fmaf(ar[i], ar[i], nnr); nnd = fmaf(ad[i], ad[i], nnd); }
  for (int sw = 0; sw < NSWEEPS; ++sw) jsweep2(ar, nnr, ad, nnd, lane);

  const float s2r = sort16(ar, lane, wl);
  const float s2d = sort16(ad, lane, wl);

  // sum_j (sigma_r - sigma_d)^2 over sorted singular values
  const float sigr = __builtin_amdgcn_sqrtf(s2r);
  const float sigd = __builtin_amdgcn_sqrtf(s2d);
  const float dd = sigr - sigd;
  float diffs = dd * dd;
#pragma unroll
  for (int st = 1; st < 16; st <<= 1) diffs += fshfl_xor(diffs, st);

  // u_rd_i = sum_j |u_r[i,j] * u_d[i,j]|  (normalize via 1/(sigr_j*sigd_j))
  const float inv = __builtin_amdgcn_rsqf(s2r * s2d);
  float prd[16];
#pragma unroll
  for (int i = 0; i < 16; ++i) prd[i] = fabsf(ar[i] * ad[i]) * inv;
#pragma unroll
  for (int st = 1; st < 16; st <<= 1) {
#pragma unroll
    for (int i = 0; i < 16; ++i) prd[i] += fshfl_xor(prd[i], st);
  }
  float sum = 0.0f, sumsq = 0.0f;
#pragma unroll
  for (int i = 0; i < 16; ++i) { sum += prd[i]; sumsq = fmaf(prd[i], prd[i], sumsq); }
  const float mean = sum * 0.0625f;
  float var = (sumsq - 16.0f * mean * mean) * (1.0f / 15.0f);  // ddof=1
  var = fmaxf(var, 0.0f);
  const float wt  = __builtin_amdgcn_sqrtf(var) * __builtin_amdgcn_rcpf(mean + 1e-9f);
  const float val = diffs * wt;

  __shared__ float blk;
  if (tid == 0) blk = 0.0f;
  __syncthreads();
  if (lane == 0) atomicAdd(&blk, val);
  __syncthreads();
  if (tid == 0) atomicAdd(&dsSum[ai], blk);   // all groups in a block share 'ai'
}

template<int CH, int HW>
__global__ __launch_bounds__(256)
void glb_kernel(const float* __restrict__ ref, const float* __restrict__ dist,
                float* __restrict__ s1Sum) {
  const int bid = blockIdx.x;                 // a*CH + ch
  const int ai  = bid / CH;
  const float4* pr = (const float4*)(ref + (size_t)bid * HW);
  const float4* pd = (const float4*)(dist + (size_t)bid * HW);
  float sr = 0.0f, sd = 0.0f;
  for (int i = threadIdx.x; i < HW / 4; i += 256) {
    const float4 r = pr[i], d = pd[i];
    sr += (r.x + r.y) + (r.z + r.w);
    sd += (d.x + d.y) + (d.z + d.w);
  }
#pragma unroll
  for (int st = 32; st >= 1; st >>= 1) { sr += __shfl_xor(sr, st, 64); sd += __shfl_xor(sd, st, 64); }
  __shared__ float bufR[4], bufD[4];
  const int w = threadIdx.x >> 6;
  if ((threadIdx.x & 63) == 0) { bufR[w] = sr; bufD[w] = sd; }
  __syncthreads();
  if (threadIdx.x == 0) {
    const float ym = (bufR[0] + bufR[1] + bufR[2] + bufR[3]) * (1.0f / HW);  // ref mean
    const float xm = (bufD[0] + bufD[1] + bufD[2] + bufD[3]) * (1.0f / HW);  // dist mean
    const float s1 = (2.0f * xm * ym + 1e-6f) / (xm * xm + ym * ym + 1e-6f);
    atomicAdd(&s1Sum[ai], s1);
  }
}

__global__ void final_kernel(const float* __restrict__ ws, float* __restrict__ out) {
  const int ai = threadIdx.x;
  if (ai < 4) {
    const float ds3 = ws[ai]      * (1.0f / (256.0f * 169.0f));
    const float ds4 = ws[4 + ai]  * (1.0f / (512.0f * 25.0f));
    const float g3  = expf(-2.0f * ws[8 + ai]  * (1.0f / 256.0f));
    const float g4  = expf(-2.0f * ws[12 + ai] * (1.0f / 512.0f));
    out[ai] = ds3 * g3 + ds4 * g4;
  }
}

extern "C" void kernel_launch(void* const* d_in, const int* in_sizes, int n_in,
                              void* d_out, int out_size, void* d_ws, size_t ws_size,
                              hipStream_t stream) {
  const float* ref3  = (const float*)d_in[0];
  const float* dist3 = (const float*)d_in[1];
  const float* ref4  = (const float*)d_in[2];
  const float* dist4 = (const float*)d_in[3];
  float* ws  = (float*)d_ws;   // [0:4) dsSum3, [4:8) dsSum4, [8:12) s1Sum3, [12:16) s1Sum4
  float* out = (float*)d_out;

  hipMemsetAsync(ws, 0, 16 * sizeof(float), stream);

  // feat3: 4*256*169 = 173056 patch pairs, 16 per block
  svd_layer_kernel<256, 64, 64, 13, 13><<<173056 / 16, 256, 0, stream>>>(ref3, dist3, ws + 0);
  // feat4: 4*512*25 = 51200 patch pairs
  svd_layer_kernel<512, 32, 32, 5, 5><<<51200 / 16, 256, 0, stream>>>(ref4, dist4, ws + 4);

  glb_kernel<256, 4096><<<4 * 256, 256, 0, stream>>>(ref3, dist3, ws + 8);
  glb_kernel<512, 1024><<<4 * 512, 256, 0, stream>>>(ref4, dist4, ws + 12);

  final_kernel<<<1, 64, 0, stream>>>(ws, out);
}

// Round 3
// 1295.842 us; speedup vs baseline: 1.9675x; 1.5455x over previous
//
#include <hip/hip_runtime.h>
#include <math.h>

#define NSWEEPS 5

__device__ __forceinline__ float fshfl_xor(float v, int m) {
  return __shfl_xor(v, m, 64);
}

// XOR-exchange within 16-lane rows. DPP (VALU pipe) where a row-level pattern
// exists; ds_swizzle BitMode (LDS pipe) otherwise.
//  xor1/2/3: quad_perm; xor7: row_half_mirror; xor8: row_ror:8 (==xor8 on 16);
//  xor15: row_mirror.
template<int R>
__device__ __forceinline__ float xexch(float v) {
  const int iv = __float_as_int(v);
  int r;
  if constexpr (R == 1)       r = __builtin_amdgcn_update_dpp(iv, iv, 0x0B1, 0xF, 0xF, true);
  else if constexpr (R == 2)  r = __builtin_amdgcn_update_dpp(iv, iv, 0x04E, 0xF, 0xF, true);
  else if constexpr (R == 3)  r = __builtin_amdgcn_update_dpp(iv, iv, 0x01B, 0xF, 0xF, true);
  else if constexpr (R == 7)  r = __builtin_amdgcn_update_dpp(iv, iv, 0x141, 0xF, 0xF, true);
  else if constexpr (R == 8)  r = __builtin_amdgcn_update_dpp(iv, iv, 0x128, 0xF, 0xF, true);
  else if constexpr (R == 15) r = __builtin_amdgcn_update_dpp(iv, iv, 0x140, 0xF, 0xF, true);
  else                        r = __builtin_amdgcn_ds_swizzle(iv, (R << 10) | 0x1F);
  return __int_as_float(r);
}

// Jacobi rotation parameters zeroing apq (Golub & Van Loan).
__device__ __forceinline__ void jrot(float apq, float app, float aqq, bool lo,
                                     float &c, float &se, float &ts) {
  float tau = (aqq - app) * __builtin_amdgcn_rcpf(2.0f * apq);
  float t = copysignf(
      __builtin_amdgcn_rcpf(fabsf(tau) + __builtin_amdgcn_sqrtf(fmaf(tau, tau, 1.0f))), tau);
  t = (apq == 0.0f) ? 0.0f : t;               // also guards the NaN path
  c = __builtin_amdgcn_rsqf(fmaf(t, t, 1.0f));
  const float s = t * c;
  se = lo ? -s : s;
  ts = lo ? -t : t;
}

// One parallel-Jacobi round over TWO independent matrices (ref & dist),
// interleaved for ILP. Pairs (lane, lane^R) within each 16-lane group.
template<int R>
__device__ __forceinline__ void jround2(float (&a)[16], float &nna,
                                        float (&b)[16], float &nnb, const int lane) {
  const float ona = xexch<R>(nna);
  const float onb = xexch<R>(nnb);
  float otha[16], othb[16];
#pragma unroll
  for (int i = 0; i < 16; ++i) otha[i] = xexch<R>(a[i]);
#pragma unroll
  for (int i = 0; i < 16; ++i) othb[i] = xexch<R>(b[i]);

  // Dot products with 4-way split accumulators (short dependency chains).
  float pa0 = 0.f, pa1 = 0.f, pa2 = 0.f, pa3 = 0.f;
  float pb0 = 0.f, pb1 = 0.f, pb2 = 0.f, pb3 = 0.f;
#pragma unroll
  for (int i = 0; i < 16; i += 4) {
    pa0 = fmaf(a[i + 0], otha[i + 0], pa0);
    pa1 = fmaf(a[i + 1], otha[i + 1], pa1);
    pa2 = fmaf(a[i + 2], otha[i + 2], pa2);
    pa3 = fmaf(a[i + 3], otha[i + 3], pa3);
    pb0 = fmaf(b[i + 0], othb[i + 0], pb0);
    pb1 = fmaf(b[i + 1], othb[i + 1], pb1);
    pb2 = fmaf(b[i + 2], othb[i + 2], pb2);
    pb3 = fmaf(b[i + 3], othb[i + 3], pb3);
  }
  const float apqa = (pa0 + pa1) + (pa2 + pa3);
  const float apqb = (pb0 + pb1) + (pb2 + pb3);

  const bool lo = lane < (lane ^ R);          // consistent p/q role in the pair
  float ca, sea, tsa, cb, seb, tsb;
  jrot(apqa, lo ? nna : ona, lo ? ona : nna, lo, ca, sea, tsa);
  jrot(apqb, lo ? nnb : onb, lo ? onb : nnb, lo, cb, seb, tsb);

#pragma unroll
  for (int i = 0; i < 16; ++i) a[i] = fmaf(ca, a[i], sea * otha[i]);
#pragma unroll
  for (int i = 0; i < 16; ++i) b[i] = fmaf(cb, b[i], seb * othb[i]);
  nna = fmaf(tsa, apqa, nna);                 // app' = app - t*apq ; aqq' = aqq + t*apq
  nnb = fmaf(tsb, apqb, nnb);
}

__device__ __forceinline__ void jsweep2(float (&a)[16], float &nna,
                                        float (&b)[16], float &nnb, const int lane) {
  jround2<1>(a, nna, b, nnb, lane);  jround2<2>(a, nna, b, nnb, lane);
  jround2<3>(a, nna, b, nnb, lane);  jround2<4>(a, nna, b, nnb, lane);
  jround2<5>(a, nna, b, nnb, lane);  jround2<6>(a, nna, b, nnb, lane);
  jround2<7>(a, nna, b, nnb, lane);  jround2<8>(a, nna, b, nnb, lane);
  jround2<9>(a, nna, b, nnb, lane);  jround2<10>(a, nna, b, nnb, lane);
  jround2<11>(a, nna, b, nnb, lane); jround2<12>(a, nna, b, nnb, lane);
  jround2<13>(a, nna, b, nnb, lane); jround2<14>(a, nna, b, nnb, lane);
  jround2<15>(a, nna, b, nnb, lane);
}

__device__ __forceinline__ void load16(const float* __restrict__ src, float (&a)[16]) {
  const float4* p = (const float4*)src;
  float4 v0 = p[0], v1 = p[1], v2 = p[2], v3 = p[3];
  a[0] = v0.x; a[1] = v0.y; a[2]  = v0.z; a[3]  = v0.w;
  a[4] = v1.x; a[5] = v1.y; a[6]  = v1.z; a[7]  = v1.w;
  a[8] = v2.x; a[9] = v2.y; a[10] = v2.z; a[11] = v2.w;
  a[12] = v3.x; a[13] = v3.y; a[14] = v3.z; a[15] = v3.w;
}

// Post-convergence: exact sigma^2 + descending sort of columns across the
// 16-lane group via ds_permute push. a[] ends at sorted position = lane.
__device__ __forceinline__ float sort16(float (&a)[16], const int lane, const int wl) {
  float s0 = 0.f, s1 = 0.f, s2v = 0.f, s3 = 0.f;
#pragma unroll
  for (int i = 0; i < 16; i += 4) {
    s0 = fmaf(a[i + 0], a[i + 0], s0);
    s1 = fmaf(a[i + 1], a[i + 1], s1);
    s2v = fmaf(a[i + 2], a[i + 2], s2v);
    s3 = fmaf(a[i + 3], a[i + 3], s3);
  }
  float s2 = (s0 + s1) + (s2v + s3);

  int rank = 0;                               // descending, stable tie-break
#pragma unroll
  for (int k = 0; k < 16; ++k) {
    const float vk = __shfl(s2, k, 16);
    rank += (vk > s2 || (vk == s2 && k < lane)) ? 1 : 0;
  }
  const int dst = (((wl & 48) | rank) << 2);  // wave-lane byte address for ds_permute (push)
#pragma unroll
  for (int i = 0; i < 16; ++i)
    a[i] = __int_as_float(__builtin_amdgcn_ds_permute(dst, __float_as_int(a[i])));
  s2 = __int_as_float(__builtin_amdgcn_ds_permute(dst, __float_as_int(s2)));
  return s2;
}

template<int CH, int H, int W, int NH, int NW>
__global__ __launch_bounds__(256)
void svd_layer_kernel(const float* __restrict__ ref, const float* __restrict__ dist,
                      float* __restrict__ dsSum) {
  constexpr int P = NH * NW;
  const int tid  = threadIdx.x;
  const int lane = tid & 15;
  const int wl   = tid & 63;
  const int pid  = blockIdx.x * 16 + (tid >> 4);
  const int ai   = pid / (CH * P);
  const int rem  = pid - ai * (CH * P);
  const int ch   = rem / P;
  const int pp   = rem - ch * P;
  const int ih   = pp / NW;
  const int iw   = pp - ih * NW;
  // patch matrix M[t][s] = x[ih*4+s, iw*4+t]; lane = column s -> row (ih*4+lane) of x
  const size_t off = (size_t)(ai * CH + ch) * (H * W) + (size_t)(ih * 4 + lane) * W + iw * 4;

  float ar[16], ad[16];
  load16(ref + off, ar);
  load16(dist + off, ad);

  float nnr = 0.f, nnd = 0.f;
#pragma unroll
  for (int i = 0; i < 16; ++i) { nnr = fmaf(ar[i], ar[i], nnr); nnd = fmaf(ad[i], ad[i], nnd); }
  for (int sw = 0; sw < NSWEEPS; ++sw) jsweep2(ar, nnr, ad, nnd, lane);

  const float s2r = sort16(ar, lane, wl);
  const float s2d = sort16(ad, lane, wl);

  // sum_j (sigma_r - sigma_d)^2 over sorted singular values
  const float sigr = __builtin_amdgcn_sqrtf(s2r);
  const float sigd = __builtin_amdgcn_sqrtf(s2d);
  const float dd = sigr - sigd;
  float diffs = dd * dd;
#pragma unroll
  for (int st = 1; st < 16; st <<= 1) diffs += fshfl_xor(diffs, st);

  // u_rd_i = sum_j |u_r[i,j] * u_d[i,j]|  (normalize via 1/(sigr_j*sigd_j))
  const float inv = __builtin_amdgcn_rsqf(s2r * s2d);
  float prd[16];
#pragma unroll
  for (int i = 0; i < 16; ++i) prd[i] = fabsf(ar[i] * ad[i]) * inv;
#pragma unroll
  for (int st = 1; st < 16; st <<= 1) {
#pragma unroll
    for (int i = 0; i < 16; ++i) prd[i] += fshfl_xor(prd[i], st);
  }
  float sum = 0.0f, sumsq = 0.0f;
#pragma unroll
  for (int i = 0; i < 16; ++i) { sum += prd[i]; sumsq = fmaf(prd[i], prd[i], sumsq); }
  const float mean = sum * 0.0625f;
  float var = (sumsq - 16.0f * mean * mean) * (1.0f / 15.0f);  // ddof=1
  var = fmaxf(var, 0.0f);
  const float wt  = __builtin_amdgcn_sqrtf(var) * __builtin_amdgcn_rcpf(mean + 1e-9f);
  const float val = diffs * wt;

  __shared__ float blk;
  if (tid == 0) blk = 0.0f;
  __syncthreads();
  if (lane == 0) atomicAdd(&blk, val);
  __syncthreads();
  if (tid == 0) atomicAdd(&dsSum[ai], blk);   // all groups in a block share 'ai'
}

template<int CH, int HW>
__global__ __launch_bounds__(256)
void glb_kernel(const float* __restrict__ ref, const float* __restrict__ dist,
                float* __restrict__ s1Sum) {
  const int bid = blockIdx.x;                 // a*CH + ch
  const int ai  = bid / CH;
  const float4* pr = (const float4*)(ref + (size_t)bid * HW);
  const float4* pd = (const float4*)(dist + (size_t)bid * HW);
  float sr = 0.0f, sd = 0.0f;
  for (int i = threadIdx.x; i < HW / 4; i += 256) {
    const float4 r = pr[i], d = pd[i];
    sr += (r.x + r.y) + (r.z + r.w);
    sd += (d.x + d.y) + (d.z + d.w);
  }
#pragma unroll
  for (int st = 32; st >= 1; st >>= 1) { sr += __shfl_xor(sr, st, 64); sd += __shfl_xor(sd, st, 64); }
  __shared__ float bufR[4], bufD[4];
  const int w = threadIdx.x >> 6;
  if ((threadIdx.x & 63) == 0) { bufR[w] = sr; bufD[w] = sd; }
  __syncthreads();
  if (threadIdx.x == 0) {
    const float ym = (bufR[0] + bufR[1] + bufR[2] + bufR[3]) * (1.0f / HW);  // ref mean
    const float xm = (bufD[0] + bufD[1] + bufD[2] + bufD[3]) * (1.0f / HW);  // dist mean
    const float s1 = (2.0f * xm * ym + 1e-6f) / (xm * xm + ym * ym + 1e-6f);
    atomicAdd(&s1Sum[ai], s1);
  }
}

__global__ void final_kernel(const float* __restrict__ ws, float* __restrict__ out) {
  const int ai = threadIdx.x;
  if (ai < 4) {
    const float ds3 = ws[ai]      * (1.0f / (256.0f * 169.0f));
    const float ds4 = ws[4 + ai]  * (1.0f / (512.0f * 25.0f));
    const float g3  = expf(-2.0f * ws[8 + ai]  * (1.0f / 256.0f));
    const float g4  = expf(-2.0f * ws[12 + ai] * (1.0f / 512.0f));
    out[ai] = ds3 * g3 + ds4 * g4;
  }
}

extern "C" void kernel_launch(void* const* d_in, const int* in_sizes, int n_in,
                              void* d_out, int out_size, void* d_ws, size_t ws_size,
                              hipStream_t stream) {
  const float* ref3  = (const float*)d_in[0];
  const float* dist3 = (const float*)d_in[1];
  const float* ref4  = (const float*)d_in[2];
  const float* dist4 = (const float*)d_in[3];
  float* ws  = (float*)d_ws;   // [0:4) dsSum3, [4:8) dsSum4, [8:12) s1Sum3, [12:16) s1Sum4
  float* out = (float*)d_out;

  hipMemsetAsync(ws, 0, 16 * sizeof(float), stream);

  // feat3: 4*256*169 = 173056 patch pairs, 16 per block
  svd_layer_kernel<256, 64, 64, 13, 13><<<173056 / 16, 256, 0, stream>>>(ref3, dist3, ws + 0);
  // feat4: 4*512*25 = 51200 patch pairs
  svd_layer_kernel<512, 32, 32, 5, 5><<<51200 / 16, 256, 0, stream>>>(ref4, dist4, ws + 4);

  glb_kernel<256, 4096><<<4 * 256, 256, 0, stream>>>(ref3, dist3, ws + 8);
  glb_kernel<512, 1024><<<4 * 512, 256, 0, stream>>>(ref4, dist4, ws + 12);

  final_kernel<<<1, 64, 0, stream>>>(ws, out);
}

// Round 4
// 1172.902 us; speedup vs baseline: 2.1737x; 1.1048x over previous
//
#include <hip/hip_runtime.h>
#include <math.h>

#define NSWEEPS 5

__device__ __forceinline__ float fshfl_xor(float v, int m) {
  return __shfl_xor(v, m, 64);
}

// XOR-exchange within 16-lane rows. DPP (VALU pipe) where a row-level pattern
// exists; ds_swizzle BitMode (LDS pipe) otherwise. Split chosen to balance the
// per-SIMD VALU pipe against the CU-shared LDS pipe (k*=6 DPP rounds).
//  xor1/2/3: quad_perm; xor7: row_half_mirror; xor8: row_ror:8; xor15: row_mirror.
template<int R>
__device__ __forceinline__ float xexch(float v) {
  const int iv = __float_as_int(v);
  int r;
  if constexpr (R == 1)       r = __builtin_amdgcn_update_dpp(iv, iv, 0x0B1, 0xF, 0xF, true);
  else if constexpr (R == 2)  r = __builtin_amdgcn_update_dpp(iv, iv, 0x04E, 0xF, 0xF, true);
  else if constexpr (R == 3)  r = __builtin_amdgcn_update_dpp(iv, iv, 0x01B, 0xF, 0xF, true);
  else if constexpr (R == 7)  r = __builtin_amdgcn_update_dpp(iv, iv, 0x141, 0xF, 0xF, true);
  else if constexpr (R == 8)  r = __builtin_amdgcn_update_dpp(iv, iv, 0x128, 0xF, 0xF, true);
  else if constexpr (R == 15) r = __builtin_amdgcn_update_dpp(iv, iv, 0x140, 0xF, 0xF, true);
  else                        r = __builtin_amdgcn_ds_swizzle(iv, (R << 10) | 0x1F);
  return __int_as_float(r);
}

// Role-free Jacobi rotation. dl = on - nn (partner norm minus own norm) has
// opposite sign on the two partner lanes, so the lane-local root t' = -t on
// the hi lane; the needed coefficients are se = -s', ts = -t' on BOTH lanes.
// t = sign(dl) * 2*apq / (|dl| + sqrt(dl^2 + 4*apq^2))  (small root; exact
// algebraic rewrite of t = sign(tau)/(|tau|+sqrt(1+tau^2)), tau = dl/(2 apq)).
__device__ __forceinline__ void jrotrf(float apq, float dl,
                                       float &t, float &c, float &sec) {
  const float p2  = apq + apq;
  const float rt  = __builtin_amdgcn_sqrtf(fmaf(dl, dl, p2 * p2));
  const float den = fabsf(dl) + rt;
  float t0 = p2 * __builtin_amdgcn_rcpf(den);
  // apply sign(dl) via signbit xor (t0 already carries sign(apq))
  t0 = __int_as_float(__float_as_int(t0) ^ (int)(__float_as_int(dl) & 0x80000000u));
  t  = (den == 0.0f) ? 0.0f : t0;            // dl==0 && apq==0 -> identity
  sec = __builtin_amdgcn_sqrtf(fmaf(t, t, 1.0f));  // 1/c
  c   = __builtin_amdgcn_rcpf(sec);
}

// One parallel-Jacobi round over TWO independent matrices (ref & dist) in
// scaled-column form: true column = d * w. Update is a single FMA per element
// (w += rc*oth, rc = -t * d_oth/d_own); the cosine folds into d' = c*d.
// nn tracks the TRUE squared column norm (sigma^2 estimate).
template<int R>
__device__ __forceinline__ void jround2s(float (&wa)[16], float &nna, float &da, float &ida,
                                         float (&wb)[16], float &nnb, float &db, float &idb) {
  const float ona = xexch<R>(nna);
  const float onb = xexch<R>(nnb);
  const float oda = xexch<R>(da);
  const float odb = xexch<R>(db);
  float otha[16], othb[16];
#pragma unroll
  for (int i = 0; i < 16; ++i) otha[i] = xexch<R>(wa[i]);
#pragma unroll
  for (int i = 0; i < 16; ++i) othb[i] = xexch<R>(wb[i]);

  // Dot products with 4-way split accumulators (short dependency chains).
  float pa0 = 0.f, pa1 = 0.f, pa2 = 0.f, pa3 = 0.f;
  float pb0 = 0.f, pb1 = 0.f, pb2 = 0.f, pb3 = 0.f;
#pragma unroll
  for (int i = 0; i < 16; i += 4) {
    pa0 = fmaf(wa[i + 0], otha[i + 0], pa0);
    pa1 = fmaf(wa[i + 1], otha[i + 1], pa1);
    pa2 = fmaf(wa[i + 2], otha[i + 2], pa2);
    pa3 = fmaf(wa[i + 3], otha[i + 3], pa3);
    pb0 = fmaf(wb[i + 0], othb[i + 0], pb0);
    pb1 = fmaf(wb[i + 1], othb[i + 1], pb1);
    pb2 = fmaf(wb[i + 2], othb[i + 2], pb2);
    pb3 = fmaf(wb[i + 3], othb[i + 3], pb3);
  }
  const float dota = (pa0 + pa1) + (pa2 + pa3);
  const float dotb = (pb0 + pb1) + (pb2 + pb3);
  const float apqa = dota * da * oda;          // true a_pq
  const float apqb = dotb * db * odb;
  const float dla  = ona - nna;
  const float dlb  = onb - nnb;

  float ta, ca, seca, tb, cb, secb;
  jrotrf(apqa, dla, ta, ca, seca);
  jrotrf(apqb, dlb, tb, cb, secb);

  const float rca = -ta * ida * oda;           // (se/c) * d_oth/d_own
  const float rcb = -tb * idb * odb;
#pragma unroll
  for (int i = 0; i < 16; ++i) wa[i] = fmaf(rca, otha[i], wa[i]);
#pragma unroll
  for (int i = 0; i < 16; ++i) wb[i] = fmaf(rcb, othb[i], wb[i]);
  da *= ca;  ida *= seca;
  db *= cb;  idb *= secb;
  nna = fmaf(-ta, apqa, nna);                  // nn' = nn + ts*apq, ts = -t'
  nnb = fmaf(-tb, apqb, nnb);
}

__device__ __forceinline__ void jsweep2s(float (&a)[16], float &nna, float &da, float &ida,
                                         float (&b)[16], float &nnb, float &db, float &idb) {
  jround2s<1>(a, nna, da, ida, b, nnb, db, idb);
  jround2s<2>(a, nna, da, ida, b, nnb, db, idb);
  jround2s<3>(a, nna, da, ida, b, nnb, db, idb);
  jround2s<4>(a, nna, da, ida, b, nnb, db, idb);
  jround2s<5>(a, nna, da, ida, b, nnb, db, idb);
  jround2s<6>(a, nna, da, ida, b, nnb, db, idb);
  jround2s<7>(a, nna, da, ida, b, nnb, db, idb);
  jround2s<8>(a, nna, da, ida, b, nnb, db, idb);
  jround2s<9>(a, nna, da, ida, b, nnb, db, idb);
  jround2s<10>(a, nna, da, ida, b, nnb, db, idb);
  jround2s<11>(a, nna, da, ida, b, nnb, db, idb);
  jround2s<12>(a, nna, da, ida, b, nnb, db, idb);
  jround2s<13>(a, nna, da, ida, b, nnb, db, idb);
  jround2s<14>(a, nna, da, ida, b, nnb, db, idb);
  jround2s<15>(a, nna, da, ida, b, nnb, db, idb);
}

__device__ __forceinline__ void load16(const float* __restrict__ src, float (&a)[16]) {
  const float4* p = (const float4*)src;
  float4 v0 = p[0], v1 = p[1], v2 = p[2], v3 = p[3];
  a[0] = v0.x; a[1] = v0.y; a[2]  = v0.z; a[3]  = v0.w;
  a[4] = v1.x; a[5] = v1.y; a[6]  = v1.z; a[7]  = v1.w;
  a[8] = v2.x; a[9] = v2.y; a[10] = v2.z; a[11] = v2.w;
  a[12] = v3.x; a[13] = v3.y; a[14] = v3.z; a[15] = v3.w;
}

// Post-convergence: true sigma^2 = d^2 * sum(w^2); descending sort of
// (w, d) columns across the 16-lane group via ds_permute push.
__device__ __forceinline__ float sort16s(float (&w)[16], float &d,
                                         const int lane, const int wl) {
  float s0 = 0.f, s1 = 0.f, s2v = 0.f, s3 = 0.f;
#pragma unroll
  for (int i = 0; i < 16; i += 4) {
    s0  = fmaf(w[i + 0], w[i + 0], s0);
    s1  = fmaf(w[i + 1], w[i + 1], s1);
    s2v = fmaf(w[i + 2], w[i + 2], s2v);
    s3  = fmaf(w[i + 3], w[i + 3], s3);
  }
  float s2 = ((s0 + s1) + (s2v + s3)) * d * d;

  int rank = 0;                               // descending, stable tie-break
#pragma unroll
  for (int k = 0; k < 16; ++k) {
    const float vk = __shfl(s2, k, 16);
    rank += (vk > s2 || (vk == s2 && k < lane)) ? 1 : 0;
  }
  const int dst = (((wl & 48) | rank) << 2);  // wave-lane byte address for ds_permute (push)
#pragma unroll
  for (int i = 0; i < 16; ++i)
    w[i] = __int_as_float(__builtin_amdgcn_ds_permute(dst, __float_as_int(w[i])));
  d  = __int_as_float(__builtin_amdgcn_ds_permute(dst, __float_as_int(d)));
  s2 = __int_as_float(__builtin_amdgcn_ds_permute(dst, __float_as_int(s2)));
  return s2;
}

template<int CH, int H, int W, int NH, int NW>
__global__ __launch_bounds__(256)
void svd_layer_kernel(const float* __restrict__ ref, const float* __restrict__ dist,
                      float* __restrict__ dsSum) {
  constexpr int P = NH * NW;
  const int tid  = threadIdx.x;
  const int lane = tid & 15;
  const int wl   = tid & 63;
  const int pid  = blockIdx.x * 16 + (tid >> 4);
  const int ai   = pid / (CH * P);
  const int rem  = pid - ai * (CH * P);
  const int ch   = rem / P;
  const int pp   = rem - ch * P;
  const int ih   = pp / NW;
  const int iw   = pp - ih * NW;
  // patch matrix M[t][s] = x[ih*4+s, iw*4+t]; lane = column s -> row (ih*4+lane) of x
  const size_t off = (size_t)(ai * CH + ch) * (H * W) + (size_t)(ih * 4 + lane) * W + iw * 4;

  float ar[16], ad[16];
  load16(ref + off, ar);
  load16(dist + off, ad);

  float nnr = 0.f, nnd = 0.f;
#pragma unroll
  for (int i = 0; i < 16; ++i) { nnr = fmaf(ar[i], ar[i], nnr); nnd = fmaf(ad[i], ad[i], nnd); }
  float dr = 1.f, idr = 1.f, dd_ = 1.f, idd = 1.f;
  for (int sw = 0; sw < NSWEEPS; ++sw) jsweep2s(ar, nnr, dr, idr, ad, nnd, dd_, idd);

  const float s2r = sort16s(ar, dr, lane, wl);
  const float s2d = sort16s(ad, dd_, lane, wl);

  // sum_j (sigma_r - sigma_d)^2 over sorted singular values
  const float sigr = __builtin_amdgcn_sqrtf(s2r);
  const float sigd = __builtin_amdgcn_sqrtf(s2d);
  const float ddv = sigr - sigd;
  float diffs = ddv * ddv;
#pragma unroll
  for (int st = 1; st < 16; st <<= 1) diffs += fshfl_xor(diffs, st);

  // u_rd_i = sum_j |u_r[i,j] * u_d[i,j]|; true col = d*w, normalize by sigma:
  // |d_r w_r * d_d w_d| / (sig_r*sig_d) = |w_r*w_d| * (d_r*d_d)*rsq(s2r*s2d)
  const float fac = dr * dd_ * __builtin_amdgcn_rsqf(s2r * s2d);
  float prd[16];
#pragma unroll
  for (int i = 0; i < 16; ++i) prd[i] = fabsf(ar[i] * ad[i]) * fac;
#pragma unroll
  for (int st = 1; st < 16; st <<= 1) {
#pragma unroll
    for (int i = 0; i < 16; ++i) prd[i] += fshfl_xor(prd[i], st);
  }
  float sum = 0.0f, sumsq = 0.0f;
#pragma unroll
  for (int i = 0; i < 16; ++i) { sum += prd[i]; sumsq = fmaf(prd[i], prd[i], sumsq); }
  const float mean = sum * 0.0625f;
  float var = (sumsq - 16.0f * mean * mean) * (1.0f / 15.0f);  // ddof=1
  var = fmaxf(var, 0.0f);
  const float wt  = __builtin_amdgcn_sqrtf(var) * __builtin_amdgcn_rcpf(mean + 1e-9f);
  const float val = diffs * wt;

  __shared__ float blk;
  if (tid == 0) blk = 0.0f;
  __syncthreads();
  if (lane == 0) atomicAdd(&blk, val);
  __syncthreads();
  if (tid == 0) atomicAdd(&dsSum[ai], blk);   // all groups in a block share 'ai'
}

template<int CH, int HW>
__global__ __launch_bounds__(256)
void glb_kernel(const float* __restrict__ ref, const float* __restrict__ dist,
                float* __restrict__ s1Sum) {
  const int bid = blockIdx.x;                 // a*CH + ch
  const int ai  = bid / CH;
  const float4* pr = (const float4*)(ref + (size_t)bid * HW);
  const float4* pd = (const float4*)(dist + (size_t)bid * HW);
  float sr = 0.0f, sd = 0.0f;
  for (int i = threadIdx.x; i < HW / 4; i += 256) {
    const float4 r = pr[i], d = pd[i];
    sr += (r.x + r.y) + (r.z + r.w);
    sd += (d.x + d.y) + (d.z + d.w);
  }
#pragma unroll
  for (int st = 32; st >= 1; st >>= 1) { sr += __shfl_xor(sr, st, 64); sd += __shfl_xor(sd, st, 64); }
  __shared__ float bufR[4], bufD[4];
  const int w = threadIdx.x >> 6;
  if ((threadIdx.x & 63) == 0) { bufR[w] = sr; bufD[w] = sd; }
  __syncthreads();
  if (threadIdx.x == 0) {
    const float ym = (bufR[0] + bufR[1] + bufR[2] + bufR[3]) * (1.0f / HW);  // ref mean
    const float xm = (bufD[0] + bufD[1] + bufD[2] + bufD[3]) * (1.0f / HW);  // dist mean
    const float s1 = (2.0f * xm * ym + 1e-6f) / (xm * xm + ym * ym + 1e-6f);
    atomicAdd(&s1Sum[ai], s1);
  }
}

__global__ void final_kernel(const float* __restrict__ ws, float* __restrict__ out) {
  const int ai = threadIdx.x;
  if (ai < 4) {
    const float ds3 = ws[ai]      * (1.0f / (256.0f * 169.0f));
    const float ds4 = ws[4 + ai]  * (1.0f / (512.0f * 25.0f));
    const float g3  = expf(-2.0f * ws[8 + ai]  * (1.0f / 256.0f));
    const float g4  = expf(-2.0f * ws[12 + ai] * (1.0f / 512.0f));
    out[ai] = ds3 * g3 + ds4 * g4;
  }
}

extern "C" void kernel_launch(void* const* d_in, const int* in_sizes, int n_in,
                              void* d_out, int out_size, void* d_ws, size_t ws_size,
                              hipStream_t stream) {
  const float* ref3  = (const float*)d_in[0];
  const float* dist3 = (const float*)d_in[1];
  const float* ref4  = (const float*)d_in[2];
  const float* dist4 = (const float*)d_in[3];
  float* ws  = (float*)d_ws;   // [0:4) dsSum3, [4:8) dsSum4, [8:12) s1Sum3, [12:16) s1Sum4
  float* out = (float*)d_out;

  hipMemsetAsync(ws, 0, 16 * sizeof(float), stream);

  // feat3: 4*256*169 = 173056 patch pairs, 16 per block
  svd_layer_kernel<256, 64, 64, 13, 13><<<173056 / 16, 256, 0, stream>>>(ref3, dist3, ws + 0);
  // feat4: 4*512*25 = 51200 patch pairs
  svd_layer_kernel<512, 32, 32, 5, 5><<<51200 / 16, 256, 0, stream>>>(ref4, dist4, ws + 4);

  glb_kernel<256, 4096><<<4 * 256, 256, 0, stream>>>(ref3, dist3, ws + 8);
  glb_kernel<512, 1024><<<4 * 512, 256, 0, stream>>>(ref4, dist4, ws + 12);

  final_kernel<<<1, 64, 0, stream>>>(ws, out);
}

// Round 5
// 842.476 us; speedup vs baseline: 3.0263x; 1.3922x over previous
//
#include <hip/hip_runtime.h>
#include <math.h>

#define NSWEEPS 5

// Packed half2 storage for Jacobi columns: one 32-bit register holds two
// matrix elements. Exchange = 1 op/2 elems, dot = v_dot2_f32_f16 (f32 acc),
// update = v_pk_fma_f16. All rotation math stays f32.
typedef _Float16 f16x2 __attribute__((ext_vector_type(2)));

__device__ __forceinline__ int h2i(f16x2 v) { int r; __builtin_memcpy(&r, &v, 4); return r; }
__device__ __forceinline__ f16x2 i2h(int v) { f16x2 r; __builtin_memcpy(&r, &v, 4); return r; }

__device__ __forceinline__ float fshfl_xor(float v, int m) {
  return __shfl_xor(v, m, 64);
}

// XOR-exchange within 16-lane rows. quad_perm DPP (VALU) for R=1,2,3;
// ds_swizzle BitMode (LDS pipe) otherwise. With packed f16x2 the LDS traffic
// is half of the f32 version, so more rounds ride the (CU-shared) LDS pipe.
template<int R>
__device__ __forceinline__ int xexch_i(int iv) {
  if constexpr (R == 1)      return __builtin_amdgcn_update_dpp(iv, iv, 0x0B1, 0xF, 0xF, true);
  else if constexpr (R == 2) return __builtin_amdgcn_update_dpp(iv, iv, 0x04E, 0xF, 0xF, true);
  else if constexpr (R == 3) return __builtin_amdgcn_update_dpp(iv, iv, 0x01B, 0xF, 0xF, true);
  else                       return __builtin_amdgcn_ds_swizzle(iv, (R << 10) | 0x1F);
}
template<int R>
__device__ __forceinline__ float xexch(float v) {
  return __int_as_float(xexch_i<R>(__float_as_int(v)));
}

// Role-free Jacobi rotation (see R3/R4 derivation). dl = on - nn flips sign
// across the pair, so se = -s', ts = -t' uniformly on both lanes.
// +1e-35 on den removes the den==0 cndmask: p2==0 -> t=0*huge=0 exactly.
__device__ __forceinline__ void jrotrf(float apq, float dl,
                                       float &t, float &c, float &sec) {
  const float p2  = apq + apq;
  const float rt  = __builtin_amdgcn_sqrtf(fmaf(dl, dl, p2 * p2));
  const float den = fabsf(dl) + rt + 1e-35f;
  const float t0  = p2 * __builtin_amdgcn_rcpf(den);
  t   = __int_as_float(__float_as_int(t0) ^ (int)(__float_as_int(dl) & 0x80000000u));
  sec = __builtin_amdgcn_sqrtf(fmaf(t, t, 1.0f));  // 1/c
  c   = __builtin_amdgcn_rcpf(sec);
}

// One parallel-Jacobi round over TWO matrices in packed scaled-column form:
// true column = d * w, w stored as 8 x f16x2. nn tracks the true sigma^2.
template<int R>
__device__ __forceinline__ void jround2p(f16x2 (&wa)[8], float &nna, float &da, float &ida,
                                         f16x2 (&wb)[8], float &nnb, float &db, float &idb) {
  const float ona = xexch<R>(nna);
  const float onb = xexch<R>(nnb);
  const float oda = xexch<R>(da);
  const float odb = xexch<R>(db);
  f16x2 oa[8], ob[8];
#pragma unroll
  for (int i = 0; i < 8; ++i) oa[i] = i2h(xexch_i<R>(h2i(wa[i])));
#pragma unroll
  for (int i = 0; i < 8; ++i) ob[i] = i2h(xexch_i<R>(h2i(wb[i])));

  // Packed dots, f32 accumulate, 4-way split chains.
  float pa0 = 0.f, pa1 = 0.f, pa2 = 0.f, pa3 = 0.f;
  float pb0 = 0.f, pb1 = 0.f, pb2 = 0.f, pb3 = 0.f;
  pa0 = __builtin_amdgcn_fdot2(wa[0], oa[0], pa0, false);
  pa1 = __builtin_amdgcn_fdot2(wa[1], oa[1], pa1, false);
  pa2 = __builtin_amdgcn_fdot2(wa[2], oa[2], pa2, false);
  pa3 = __builtin_amdgcn_fdot2(wa[3], oa[3], pa3, false);
  pb0 = __builtin_amdgcn_fdot2(wb[0], ob[0], pb0, false);
  pb1 = __builtin_amdgcn_fdot2(wb[1], ob[1], pb1, false);
  pb2 = __builtin_amdgcn_fdot2(wb[2], ob[2], pb2, false);
  pb3 = __builtin_amdgcn_fdot2(wb[3], ob[3], pb3, false);
  pa0 = __builtin_amdgcn_fdot2(wa[4], oa[4], pa0, false);
  pa1 = __builtin_amdgcn_fdot2(wa[5], oa[5], pa1, false);
  pa2 = __builtin_amdgcn_fdot2(wa[6], oa[6], pa2, false);
  pa3 = __builtin_amdgcn_fdot2(wa[7], oa[7], pa3, false);
  pb0 = __builtin_amdgcn_fdot2(wb[4], ob[4], pb0, false);
  pb1 = __builtin_amdgcn_fdot2(wb[5], ob[5], pb1, false);
  pb2 = __builtin_amdgcn_fdot2(wb[6], ob[6], pb2, false);
  pb3 = __builtin_amdgcn_fdot2(wb[7], ob[7], pb3, false);
  const float dota = (pa0 + pa1) + (pa2 + pa3);
  const float dotb = (pb0 + pb1) + (pb2 + pb3);

  const float apqa = dota * da * oda;           // true a_pq
  const float apqb = dotb * db * odb;
  const float dla  = ona - nna;
  const float dlb  = onb - nnb;

  float ta, ca, seca, tb, cb, secb;
  jrotrf(apqa, dla, ta, ca, seca);
  jrotrf(apqb, dlb, tb, cb, secb);

  const float rca = -ta * ida * oda;
  const float rcb = -tb * idb * odb;
  const _Float16 hra = (_Float16)rca;           // RNE cast (avoid RTZ bias)
  const _Float16 hrb = (_Float16)rcb;
  const f16x2 ra = {hra, hra};
  const f16x2 rb = {hrb, hrb};
#pragma unroll
  for (int i = 0; i < 8; ++i) wa[i] = __builtin_elementwise_fma(ra, oa[i], wa[i]);
#pragma unroll
  for (int i = 0; i < 8; ++i) wb[i] = __builtin_elementwise_fma(rb, ob[i], wb[i]);
  da *= ca;  ida *= seca;
  db *= cb;  idb *= secb;
  nna = fmaf(-ta, apqa, nna);
  nnb = fmaf(-tb, apqb, nnb);
}

// One sweep (all 15 XOR rounds) + refold: fold d into storage so d stays in
// [0.0055,1] within a sweep -> |w| <= ~1500, safely inside f16 range.
__device__ __forceinline__ void jsweep2p(f16x2 (&a)[8], float &nna, float &da, float &ida,
                                         f16x2 (&b)[8], float &nnb, float &db, float &idb) {
  jround2p<1>(a, nna, da, ida, b, nnb, db, idb);
  jround2p<2>(a, nna, da, ida, b, nnb, db, idb);
  jround2p<3>(a, nna, da, ida, b, nnb, db, idb);
  jround2p<4>(a, nna, da, ida, b, nnb, db, idb);
  jround2p<5>(a, nna, da, ida, b, nnb, db, idb);
  jround2p<6>(a, nna, da, ida, b, nnb, db, idb);
  jround2p<7>(a, nna, da, ida, b, nnb, db, idb);
  jround2p<8>(a, nna, da, ida, b, nnb, db, idb);
  jround2p<9>(a, nna, da, ida, b, nnb, db, idb);
  jround2p<10>(a, nna, da, ida, b, nnb, db, idb);
  jround2p<11>(a, nna, da, ida, b, nnb, db, idb);
  jround2p<12>(a, nna, da, ida, b, nnb, db, idb);
  jround2p<13>(a, nna, da, ida, b, nnb, db, idb);
  jround2p<14>(a, nna, da, ida, b, nnb, db, idb);
  jround2p<15>(a, nna, da, ida, b, nnb, db, idb);
  const _Float16 hda = (_Float16)da;
  const _Float16 hdb = (_Float16)db;
  const f16x2 sa = {hda, hda};
  const f16x2 sb = {hdb, hdb};
#pragma unroll
  for (int i = 0; i < 8; ++i) a[i] *= sa;
#pragma unroll
  for (int i = 0; i < 8; ++i) b[i] *= sb;
  da = 1.f; ida = 1.f; db = 1.f; idb = 1.f;     // nn unchanged (true norm)
}

__device__ __forceinline__ void load16(const float* __restrict__ src, float (&a)[16]) {
  const float4* p = (const float4*)src;
  float4 v0 = p[0], v1 = p[1], v2 = p[2], v3 = p[3];
  a[0] = v0.x; a[1] = v0.y; a[2]  = v0.z; a[3]  = v0.w;
  a[4] = v1.x; a[5] = v1.y; a[6]  = v1.z; a[7]  = v1.w;
  a[8] = v2.x; a[9] = v2.y; a[10] = v2.z; a[11] = v2.w;
  a[12] = v3.x; a[13] = v3.y; a[14] = v3.z; a[15] = v3.w;
}

// Post-convergence (d==1 after final refold): sigma^2 = sum(w^2); descending
// sort of columns across the 16-lane group via ds_permute push.
__device__ __forceinline__ float sort16(float (&w)[16], const int lane, const int wl) {
  float s0 = 0.f, s1 = 0.f, s2v = 0.f, s3 = 0.f;
#pragma unroll
  for (int i = 0; i < 16; i += 4) {
    s0  = fmaf(w[i + 0], w[i + 0], s0);
    s1  = fmaf(w[i + 1], w[i + 1], s1);
    s2v = fmaf(w[i + 2], w[i + 2], s2v);
    s3  = fmaf(w[i + 3], w[i + 3], s3);
  }
  float s2 = (s0 + s1) + (s2v + s3);

  int rank = 0;                               // descending, stable tie-break
#pragma unroll
  for (int k = 0; k < 16; ++k) {
    const float vk = __shfl(s2, k, 16);
    rank += (vk > s2 || (vk == s2 && k < lane)) ? 1 : 0;
  }
  const int dst = (((wl & 48) | rank) << 2);  // wave-lane byte addr, ds_permute push
#pragma unroll
  for (int i = 0; i < 16; ++i)
    w[i] = __int_as_float(__builtin_amdgcn_ds_permute(dst, __float_as_int(w[i])));
  s2 = __int_as_float(__builtin_amdgcn_ds_permute(dst, __float_as_int(s2)));
  return s2;
}

template<int CH, int H, int W, int NH, int NW>
__global__ __launch_bounds__(256)
void svd_layer_kernel(const float* __restrict__ ref, const float* __restrict__ dist,
                      float* __restrict__ dsSum) {
  constexpr int P = NH * NW;
  const int tid  = threadIdx.x;
  const int lane = tid & 15;
  const int wl   = tid & 63;
  const int pid  = blockIdx.x * 16 + (tid >> 4);
  const int ai   = pid / (CH * P);
  const int rem  = pid - ai * (CH * P);
  const int ch   = rem / P;
  const int pp   = rem - ch * P;
  const int ih   = pp / NW;
  const int iw   = pp - ih * NW;
  // patch matrix M[t][s] = x[ih*4+s, iw*4+t]; lane = column s -> row (ih*4+lane) of x
  const size_t off = (size_t)(ai * CH + ch) * (H * W) + (size_t)(ih * 4 + lane) * W + iw * 4;

  float tr[16], td[16];
  load16(ref + off, tr);
  load16(dist + off, td);

  float nnr = 0.f, nnd = 0.f;
#pragma unroll
  for (int i = 0; i < 16; ++i) { nnr = fmaf(tr[i], tr[i], nnr); nnd = fmaf(td[i], td[i], nnd); }

  f16x2 wr[8], wd[8];
#pragma unroll
  for (int i = 0; i < 8; ++i) {
    wr[i] = f16x2{(_Float16)tr[2 * i], (_Float16)tr[2 * i + 1]};  // RNE
    wd[i] = f16x2{(_Float16)td[2 * i], (_Float16)td[2 * i + 1]};
  }

  float dr = 1.f, idr = 1.f, dd_ = 1.f, idd = 1.f;
  for (int sw = 0; sw < NSWEEPS; ++sw) jsweep2p(wr, nnr, dr, idr, wd, nnd, dd_, idd);

  float ar[16], ad[16];
#pragma unroll
  for (int i = 0; i < 8; ++i) {
    ar[2 * i] = (float)wr[i][0]; ar[2 * i + 1] = (float)wr[i][1];
    ad[2 * i] = (float)wd[i][0]; ad[2 * i + 1] = (float)wd[i][1];
  }

  const float s2r = sort16(ar, lane, wl);
  const float s2d = sort16(ad, lane, wl);

  // sum_j (sigma_r - sigma_d)^2 over sorted singular values
  const float sigr = __builtin_amdgcn_sqrtf(s2r);
  const float sigd = __builtin_amdgcn_sqrtf(s2d);
  const float ddv = sigr - sigd;
  float diffs = ddv * ddv;
#pragma unroll
  for (int st = 1; st < 16; st <<= 1) diffs += fshfl_xor(diffs, st);

  // u_rd_i = sum_j |u_r[i,j] * u_d[i,j]| with u = col/sigma
  const float fac = __builtin_amdgcn_rsqf(s2r * s2d);
  float prd[16];
#pragma unroll
  for (int i = 0; i < 16; ++i) prd[i] = fabsf(ar[i] * ad[i]) * fac;
#pragma unroll
  for (int st = 1; st < 16; st <<= 1) {
#pragma unroll
    for (int i = 0; i < 16; ++i) prd[i] += fshfl_xor(prd[i], st);
  }
  float sum = 0.0f, sumsq = 0.0f;
#pragma unroll
  for (int i = 0; i < 16; ++i) { sum += prd[i]; sumsq = fmaf(prd[i], prd[i], sumsq); }
  const float mean = sum * 0.0625f;
  float var = (sumsq - 16.0f * mean * mean) * (1.0f / 15.0f);  // ddof=1
  var = fmaxf(var, 0.0f);
  const float wt  = __builtin_amdgcn_sqrtf(var) * __builtin_amdgcn_rcpf(mean + 1e-9f);
  const float val = diffs * wt;

  __shared__ float blk;
  if (tid == 0) blk = 0.0f;
  __syncthreads();
  if (lane == 0) atomicAdd(&blk, val);
  __syncthreads();
  if (tid == 0) atomicAdd(&dsSum[ai], blk);   // all groups in a block share 'ai'
}

template<int CH, int HW>
__global__ __launch_bounds__(256)
void glb_kernel(const float* __restrict__ ref, const float* __restrict__ dist,
                float* __restrict__ s1Sum) {
  const int bid = blockIdx.x;                 // a*CH + ch
  const int ai  = bid / CH;
  const float4* pr = (const float4*)(ref + (size_t)bid * HW);
  const float4* pd = (const float4*)(dist + (size_t)bid * HW);
  float sr = 0.0f, sd = 0.0f;
  for (int i = threadIdx.x; i < HW / 4; i += 256) {
    const float4 r = pr[i], d = pd[i];
    sr += (r.x + r.y) + (r.z + r.w);
    sd += (d.x + d.y) + (d.z + d.w);
  }
#pragma unroll
  for (int st = 32; st >= 1; st >>= 1) { sr += __shfl_xor(sr, st, 64); sd += __shfl_xor(sd, st, 64); }
  __shared__ float bufR[4], bufD[4];
  const int w = threadIdx.x >> 6;
  if ((threadIdx.x & 63) == 0) { bufR[w] = sr; bufD[w] = sd; }
  __syncthreads();
  if (threadIdx.x == 0) {
    const float ym = (bufR[0] + bufR[1] + bufR[2] + bufR[3]) * (1.0f / HW);  // ref mean
    const float xm = (bufD[0] + bufD[1] + bufD[2] + bufD[3]) * (1.0f / HW);  // dist mean
    const float s1 = (2.0f * xm * ym + 1e-6f) / (xm * xm + ym * ym + 1e-6f);
    atomicAdd(&s1Sum[ai], s1);
  }
}

__global__ void final_kernel(const float* __restrict__ ws, float* __restrict__ out) {
  const int ai = threadIdx.x;
  if (ai < 4) {
    const float ds3 = ws[ai]      * (1.0f / (256.0f * 169.0f));
    const float ds4 = ws[4 + ai]  * (1.0f / (512.0f * 25.0f));
    const float g3  = expf(-2.0f * ws[8 + ai]  * (1.0f / 256.0f));
    const float g4  = expf(-2.0f * ws[12 + ai] * (1.0f / 512.0f));
    out[ai] = ds3 * g3 + ds4 * g4;
  }
}

extern "C" void kernel_launch(void* const* d_in, const int* in_sizes, int n_in,
                              void* d_out, int out_size, void* d_ws, size_t ws_size,
                              hipStream_t stream) {
  const float* ref3  = (const float*)d_in[0];
  const float* dist3 = (const float*)d_in[1];
  const float* ref4  = (const float*)d_in[2];
  const float* dist4 = (const float*)d_in[3];
  float* ws  = (float*)d_ws;   // [0:4) dsSum3, [4:8) dsSum4, [8:12) s1Sum3, [12:16) s1Sum4
  float* out = (float*)d_out;

  hipMemsetAsync(ws, 0, 16 * sizeof(float), stream);

  // feat3: 4*256*169 = 173056 patch pairs, 16 per block
  svd_layer_kernel<256, 64, 64, 13, 13><<<173056 / 16, 256, 0, stream>>>(ref3, dist3, ws + 0);
  // feat4: 4*512*25 = 51200 patch pairs
  svd_layer_kernel<512, 32, 32, 5, 5><<<51200 / 16, 256, 0, stream>>>(ref4, dist4, ws + 4);

  glb_kernel<256, 4096><<<4 * 256, 256, 0, stream>>>(ref3, dist3, ws + 8);
  glb_kernel<512, 1024><<<4 * 512, 256, 0, stream>>>(ref4, dist4, ws + 12);

  final_kernel<<<1, 64, 0, stream>>>(ws, out);
}

// Round 6
// 680.090 us; speedup vs baseline: 3.7489x; 1.2388x over previous
//
#include <hip/hip_runtime.h>
#include <math.h>

#define NSWEEPS 4

// Packed half2 storage for Jacobi columns: one 32-bit register holds two
// matrix elements. Exchange = 1 op/2 elems, dot = v_dot2_f32_f16 (f32 acc),
// update = v_pk_fma_f16. Rotation math is f32, packed across the ref/dist
// pair as float2 to invite v_pk_*_f32 (dual-issue fp32) codegen.
typedef _Float16 f16x2 __attribute__((ext_vector_type(2)));
typedef float    f32x2 __attribute__((ext_vector_type(2)));

__device__ __forceinline__ int h2i(f16x2 v) { int r; __builtin_memcpy(&r, &v, 4); return r; }
__device__ __forceinline__ f16x2 i2h(int v) { f16x2 r; __builtin_memcpy(&r, &v, 4); return r; }

__device__ __forceinline__ f32x2 rcp2(f32x2 v) {
  return f32x2{__builtin_amdgcn_rcpf(v.x), __builtin_amdgcn_rcpf(v.y)};
}
__device__ __forceinline__ f32x2 sqrt2(f32x2 v) {
  return f32x2{__builtin_amdgcn_sqrtf(v.x), __builtin_amdgcn_sqrtf(v.y)};
}
__device__ __forceinline__ f32x2 cpsgn2(f32x2 m, f32x2 s) {
  return f32x2{copysignf(m.x, s.x), copysignf(m.y, s.y)};  // v_bfi_b32 each
}

__device__ __forceinline__ float fshfl_xor(float v, int m) {
  return __shfl_xor(v, m, 64);
}

// XOR-exchange within 16-lane rows. DPP (VALU pipe) for R in {1,2,3,7,8};
// ds_swizzle BitMode (CU-shared LDS pipe) otherwise. Split chosen to balance
// VALU (~1880 cyc/SIMD/sweep) against LDS (~1600 cyc/CU/sweep).
//  xor1/2/3: quad_perm; xor7: row_half_mirror; xor8: row_ror:8.
template<int R>
__device__ __forceinline__ int xexch_i(int iv) {
  if constexpr (R == 1)      return __builtin_amdgcn_update_dpp(iv, iv, 0x0B1, 0xF, 0xF, true);
  else if constexpr (R == 2) return __builtin_amdgcn_update_dpp(iv, iv, 0x04E, 0xF, 0xF, true);
  else if constexpr (R == 3) return __builtin_amdgcn_update_dpp(iv, iv, 0x01B, 0xF, 0xF, true);
  else if constexpr (R == 7) return __builtin_amdgcn_update_dpp(iv, iv, 0x141, 0xF, 0xF, true);
  else if constexpr (R == 8) return __builtin_amdgcn_update_dpp(iv, iv, 0x128, 0xF, 0xF, true);
  else                       return __builtin_amdgcn_ds_swizzle(iv, (R << 10) | 0x1F);
}
template<int R>
__device__ __forceinline__ float xexch(float v) {
  return __int_as_float(xexch_i<R>(__float_as_int(v)));
}

// One parallel-Jacobi round over TWO matrices (ref=lane .x, dist=lane .y of
// the packed f32x2 state) in packed scaled-column form: true column = d * w,
// w stored as 8 x f16x2. nn tracks the true sigma^2.
// Role-free rotation: dl = on - nn flips sign across the pair, so
// t = p2 / (dl + copysign(rt, dl)) is antisymmetric, and se = -s', ts = -t'
// hold uniformly on both lanes (see R3/R4 derivation). The +1e-37 inside the
// sqrt keeps den != 0 when dl = apq = 0 (identity rotation, t = 0).
template<int R>
__device__ __forceinline__ void jround2p(f16x2 (&wa)[8], f16x2 (&wb)[8],
                                         f32x2 &nn, f32x2 &d, f32x2 &id) {
  const f32x2 on = {xexch<R>(nn.x), xexch<R>(nn.y)};
  const f32x2 od = {xexch<R>(d.x),  xexch<R>(d.y)};
  f16x2 oa[8], ob[8];
#pragma unroll
  for (int i = 0; i < 8; ++i) oa[i] = i2h(xexch_i<R>(h2i(wa[i])));
#pragma unroll
  for (int i = 0; i < 8; ++i) ob[i] = i2h(xexch_i<R>(h2i(wb[i])));

  // Packed dots, f32 accumulate, 4-way split chains.
  float pa0 = 0.f, pa1 = 0.f, pa2 = 0.f, pa3 = 0.f;
  float pb0 = 0.f, pb1 = 0.f, pb2 = 0.f, pb3 = 0.f;
  pa0 = __builtin_amdgcn_fdot2(wa[0], oa[0], pa0, false);
  pa1 = __builtin_amdgcn_fdot2(wa[1], oa[1], pa1, false);
  pa2 = __builtin_amdgcn_fdot2(wa[2], oa[2], pa2, false);
  pa3 = __builtin_amdgcn_fdot2(wa[3], oa[3], pa3, false);
  pb0 = __builtin_amdgcn_fdot2(wb[0], ob[0], pb0, false);
  pb1 = __builtin_amdgcn_fdot2(wb[1], ob[1], pb1, false);
  pb2 = __builtin_amdgcn_fdot2(wb[2], ob[2], pb2, false);
  pb3 = __builtin_amdgcn_fdot2(wb[3], ob[3], pb3, false);
  pa0 = __builtin_amdgcn_fdot2(wa[4], oa[4], pa0, false);
  pa1 = __builtin_amdgcn_fdot2(wa[5], oa[5], pa1, false);
  pa2 = __builtin_amdgcn_fdot2(wa[6], oa[6], pa2, false);
  pa3 = __builtin_amdgcn_fdot2(wa[7], oa[7], pa3, false);
  pb0 = __builtin_amdgcn_fdot2(wb[4], ob[4], pb0, false);
  pb1 = __builtin_amdgcn_fdot2(wb[5], ob[5], pb1, false);
  pb2 = __builtin_amdgcn_fdot2(wb[6], ob[6], pb2, false);
  pb3 = __builtin_amdgcn_fdot2(wb[7], ob[7], pb3, false);
  const f32x2 dot = {(pa0 + pa1) + (pa2 + pa3), (pb0 + pb1) + (pb2 + pb3)};

  const f32x2 dod = d * od;
  const f32x2 apq = dot * dod;                 // true a_pq
  const f32x2 dl  = on - nn;
  const f32x2 p2  = apq + apq;
  const f32x2 rt  = sqrt2(dl * dl + p2 * p2 + 1e-37f);
  const f32x2 den = dl + cpsgn2(rt, dl);
  const f32x2 t   = p2 * rcp2(den);
  const f32x2 sec = sqrt2(t * t + 1.0f);       // 1/c
  const f32x2 c   = rcp2(sec);
  const f32x2 rc  = -t * (id * od);            // (se/c) * d_oth/d_own

  const _Float16 hra = (_Float16)rc.x;         // RNE casts (avoid RTZ bias)
  const _Float16 hrb = (_Float16)rc.y;
  const f16x2 ra = {hra, hra};
  const f16x2 rb = {hrb, hrb};
#pragma unroll
  for (int i = 0; i < 8; ++i) wa[i] = __builtin_elementwise_fma(ra, oa[i], wa[i]);
#pragma unroll
  for (int i = 0; i < 8; ++i) wb[i] = __builtin_elementwise_fma(rb, ob[i], wb[i]);
  d  *= c;
  id *= sec;
  nn  = nn - t * apq;                          // nn' = nn + ts*apq, ts = -t'
}

// One sweep (all 15 XOR rounds) + refold: fold d into storage so d stays in
// [0.0055,1] within a sweep -> |w| <= ~1500, safely inside f16 range.
__device__ __forceinline__ void jsweep2p(f16x2 (&a)[8], f16x2 (&b)[8],
                                         f32x2 &nn, f32x2 &d, f32x2 &id) {
  jround2p<1>(a, b, nn, d, id);
  jround2p<2>(a, b, nn, d, id);
  jround2p<3>(a, b, nn, d, id);
  jround2p<4>(a, b, nn, d, id);
  jround2p<5>(a, b, nn, d, id);
  jround2p<6>(a, b, nn, d, id);
  jround2p<7>(a, b, nn, d, id);
  jround2p<8>(a, b, nn, d, id);
  jround2p<9>(a, b, nn, d, id);
  jround2p<10>(a, b, nn, d, id);
  jround2p<11>(a, b, nn, d, id);
  jround2p<12>(a, b, nn, d, id);
  jround2p<13>(a, b, nn, d, id);
  jround2p<14>(a, b, nn, d, id);
  jround2p<15>(a, b, nn, d, id);
  const _Float16 hda = (_Float16)d.x;
  const _Float16 hdb = (_Float16)d.y;
  const f16x2 sa = {hda, hda};
  const f16x2 sb = {hdb, hdb};
#pragma unroll
  for (int i = 0; i < 8; ++i) a[i] *= sa;
#pragma unroll
  for (int i = 0; i < 8; ++i) b[i] *= sb;
  d = f32x2{1.f, 1.f}; id = f32x2{1.f, 1.f};   // nn unchanged (true norm)
}

__device__ __forceinline__ void load16(const float* __restrict__ src, float (&a)[16]) {
  const float4* p = (const float4*)src;
  float4 v0 = p[0], v1 = p[1], v2 = p[2], v3 = p[3];
  a[0] = v0.x; a[1] = v0.y; a[2]  = v0.z; a[3]  = v0.w;
  a[4] = v1.x; a[5] = v1.y; a[6]  = v1.z; a[7]  = v1.w;
  a[8] = v2.x; a[9] = v2.y; a[10] = v2.z; a[11] = v2.w;
  a[12] = v3.x; a[13] = v3.y; a[14] = v3.z; a[15] = v3.w;
}

// Post-convergence (d==1 after final refold): sigma^2 = sum(w^2); descending
// sort of columns across the 16-lane group via ds_permute push.
__device__ __forceinline__ float sort16(float (&w)[16], const int lane, const int wl) {
  float s0 = 0.f, s1 = 0.f, s2v = 0.f, s3 = 0.f;
#pragma unroll
  for (int i = 0; i < 16; i += 4) {
    s0  = fmaf(w[i + 0], w[i + 0], s0);
    s1  = fmaf(w[i + 1], w[i + 1], s1);
    s2v = fmaf(w[i + 2], w[i + 2], s2v);
    s3  = fmaf(w[i + 3], w[i + 3], s3);
  }
  float s2 = (s0 + s1) + (s2v + s3);

  int rank = 0;                               // descending, stable tie-break
#pragma unroll
  for (int k = 0; k < 16; ++k) {
    const float vk = __shfl(s2, k, 16);
    rank += (vk > s2 || (vk == s2 && k < lane)) ? 1 : 0;
  }
  const int dst = (((wl & 48) | rank) << 2);  // wave-lane byte addr, ds_permute push
#pragma unroll
  for (int i = 0; i < 16; ++i)
    w[i] = __int_as_float(__builtin_amdgcn_ds_permute(dst, __float_as_int(w[i])));
  s2 = __int_as_float(__builtin_amdgcn_ds_permute(dst, __float_as_int(s2)));
  return s2;
}

template<int CH, int H, int W, int NH, int NW>
__global__ __launch_bounds__(256)
void svd_layer_kernel(const float* __restrict__ ref, const float* __restrict__ dist,
                      float* __restrict__ dsSum) {
  constexpr int P = NH * NW;
  const int tid  = threadIdx.x;
  const int lane = tid & 15;
  const int wl   = tid & 63;
  const int pid  = blockIdx.x * 16 + (tid >> 4);
  const int ai   = pid / (CH * P);
  const int rem  = pid - ai * (CH * P);
  const int ch   = rem / P;
  const int pp   = rem - ch * P;
  const int ih   = pp / NW;
  const int iw   = pp - ih * NW;
  // patch matrix M[t][s] = x[ih*4+s, iw*4+t]; lane = column s -> row (ih*4+lane) of x
  const size_t off = (size_t)(ai * CH + ch) * (H * W) + (size_t)(ih * 4 + lane) * W + iw * 4;

  float tr[16], td[16];
  load16(ref + off, tr);
  load16(dist + off, td);

  float nnr = 0.f, nnd = 0.f;
#pragma unroll
  for (int i = 0; i < 16; ++i) { nnr = fmaf(tr[i], tr[i], nnr); nnd = fmaf(td[i], td[i], nnd); }

  f16x2 wr[8], wd[8];
#pragma unroll
  for (int i = 0; i < 8; ++i) {
    wr[i] = f16x2{(_Float16)tr[2 * i], (_Float16)tr[2 * i + 1]};  // RNE
    wd[i] = f16x2{(_Float16)td[2 * i], (_Float16)td[2 * i + 1]};
  }

  f32x2 nn = {nnr, nnd};
  f32x2 d  = {1.f, 1.f};
  f32x2 id = {1.f, 1.f};
  for (int sw = 0; sw < NSWEEPS; ++sw) jsweep2p(wr, wd, nn, d, id);

  float ar[16], ad[16];
#pragma unroll
  for (int i = 0; i < 8; ++i) {
    ar[2 * i] = (float)wr[i][0]; ar[2 * i + 1] = (float)wr[i][1];
    ad[2 * i] = (float)wd[i][0]; ad[2 * i + 1] = (float)wd[i][1];
  }

  const float s2r = sort16(ar, lane, wl);
  const float s2d = sort16(ad, lane, wl);

  // sum_j (sigma_r - sigma_d)^2 over sorted singular values
  const float sigr = __builtin_amdgcn_sqrtf(s2r);
  const float sigd = __builtin_amdgcn_sqrtf(s2d);
  const float ddv = sigr - sigd;
  float diffs = ddv * ddv;
#pragma unroll
  for (int st = 1; st < 16; st <<= 1) diffs += fshfl_xor(diffs, st);

  // u_rd_i = sum_j |u_r[i,j] * u_d[i,j]| with u = col/sigma
  const float fac = __builtin_amdgcn_rsqf(s2r * s2d);
  float prd[16];
#pragma unroll
  for (int i = 0; i < 16; ++i) prd[i] = fabsf(ar[i] * ad[i]) * fac;
#pragma unroll
  for (int st = 1; st < 16; st <<= 1) {
#pragma unroll
    for (int i = 0; i < 16; ++i) prd[i] += fshfl_xor(prd[i], st);
  }
  float sum = 0.0f, sumsq = 0.0f;
#pragma unroll
  for (int i = 0; i < 16; ++i) { sum += prd[i]; sumsq = fmaf(prd[i], prd[i], sumsq); }
  const float mean = sum * 0.0625f;
  float var = (sumsq - 16.0f * mean * mean) * (1.0f / 15.0f);  // ddof=1
  var = fmaxf(var, 0.0f);
  const float wt  = __builtin_amdgcn_sqrtf(var) * __builtin_amdgcn_rcpf(mean + 1e-9f);
  const float val = diffs * wt;

  __shared__ float blk;
  if (tid == 0) blk = 0.0f;
  __syncthreads();
  if (lane == 0) atomicAdd(&blk, val);
  __syncthreads();
  if (tid == 0) atomicAdd(&dsSum[ai], blk);   // all groups in a block share 'ai'
}

template<int CH, int HW>
__global__ __launch_bounds__(256)
void glb_kernel(const float* __restrict__ ref, const float* __restrict__ dist,
                float* __restrict__ s1Sum) {
  const int bid = blockIdx.x;                 // a*CH + ch
  const int ai  = bid / CH;
  const float4* pr = (const float4*)(ref + (size_t)bid * HW);
  const float4* pd = (const float4*)(dist + (size_t)bid * HW);
  float sr = 0.0f, sd = 0.0f;
  for (int i = threadIdx.x; i < HW / 4; i += 256) {
    const float4 r = pr[i], d = pd[i];
    sr += (r.x + r.y) + (r.z + r.w);
    sd += (d.x + d.y) + (d.z + d.w);
  }
#pragma unroll
  for (int st = 32; st >= 1; st >>= 1) { sr += __shfl_xor(sr, st, 64); sd += __shfl_xor(sd, st, 64); }
  __shared__ float bufR[4], bufD[4];
  const int w = threadIdx.x >> 6;
  if ((threadIdx.x & 63) == 0) { bufR[w] = sr; bufD[w] = sd; }
  __syncthreads();
  if (threadIdx.x == 0) {
    const float ym = (bufR[0] + bufR[1] + bufR[2] + bufR[3]) * (1.0f / HW);  // ref mean
    const float xm = (bufD[0] + bufD[1] + bufD[2] + bufD[3]) * (1.0f / HW);  // dist mean
    const float s1 = (2.0f * xm * ym + 1e-6f) / (xm * xm + ym * ym + 1e-6f);
    atomicAdd(&s1Sum[ai], s1);
  }
}

__global__ void final_kernel(const float* __restrict__ ws, float* __restrict__ out) {
  const int ai = threadIdx.x;
  if (ai < 4) {
    const float ds3 = ws[ai]      * (1.0f / (256.0f * 169.0f));
    const float ds4 = ws[4 + ai]  * (1.0f / (512.0f * 25.0f));
    const float g3  = expf(-2.0f * ws[8 + ai]  * (1.0f / 256.0f));
    const float g4  = expf(-2.0f * ws[12 + ai] * (1.0f / 512.0f));
    out[ai] = ds3 * g3 + ds4 * g4;
  }
}

extern "C" void kernel_launch(void* const* d_in, const int* in_sizes, int n_in,
                              void* d_out, int out_size, void* d_ws, size_t ws_size,
                              hipStream_t stream) {
  const float* ref3  = (const float*)d_in[0];
  const float* dist3 = (const float*)d_in[1];
  const float* ref4  = (const float*)d_in[2];
  const float* dist4 = (const float*)d_in[3];
  float* ws  = (float*)d_ws;   // [0:4) dsSum3, [4:8) dsSum4, [8:12) s1Sum3, [12:16) s1Sum4
  float* out = (float*)d_out;

  hipMemsetAsync(ws, 0, 16 * sizeof(float), stream);

  // feat3: 4*256*169 = 173056 patch pairs, 16 per block
  svd_layer_kernel<256, 64, 64, 13, 13><<<173056 / 16, 256, 0, stream>>>(ref3, dist3, ws + 0);
  // feat4: 4*512*25 = 51200 patch pairs
  svd_layer_kernel<512, 32, 32, 5, 5><<<51200 / 16, 256, 0, stream>>>(ref4, dist4, ws + 4);

  glb_kernel<256, 4096><<<4 * 256, 256, 0, stream>>>(ref3, dist3, ws + 8);
  glb_kernel<512, 1024><<<4 * 512, 256, 0, stream>>>(ref4, dist4, ws + 12);

  final_kernel<<<1, 64, 0, stream>>>(ws, out);
}